// Round 4
// baseline (2124.947 us; speedup 1.0000x reference)
//
#include <hip/hip_runtime.h>

#define N_IN   262144
#define N_OUT  262144
#define KOFF   27
#define MPAIR  131072
#define C      64
#define EPS    1e-5f
#define NEG_SLOPE 0.01f

// ---- bucketed-merge parameters -------------------------------------------
#define BROWS   128                   // output rows per bucket
#define NBUCKET (N_OUT / BROWS)       // 2048
#define NKEY    (NBUCKET * KOFF)      // 55296 (bucket-major, k minor)
#define SLOTS   128                   // per-key capacity; lambda=64, P(ovfl)~1e-13
#define TS      129                   // tile row stride (odd -> banks spread)
#define DUMP    (64 * TS)             // dump area base for inactive lanes

// ---------------------------------------------------------------------------
// Phase 0: transpose W[k][cin][cout] -> WT[k][cout][cin] (scalar-friendly).
// ---------------------------------------------------------------------------
__global__ __launch_bounds__(256) void wt_kernel(
    const float* __restrict__ W, float* __restrict__ WT)
{
    const int k  = blockIdx.x;
    __shared__ float t[64][65];
    const int c  = threadIdx.x & 63;
    const int r0 = threadIdx.x >> 6;
    #pragma unroll
    for (int rr = 0; rr < 16; ++rr) {
        const int i = rr * 4 + r0;
        t[i][c] = W[(size_t)k * C * C + i * C + c];
    }
    __syncthreads();
    #pragma unroll
    for (int rr = 0; rr < 16; ++rr) {
        const int cc = rr * 4 + r0;                  // output channel
        WT[((size_t)k * C + cc) * C + c] = t[c][cc]; // = W[k][c][cc]
    }
}

// ---------------------------------------------------------------------------
// Phase 1: bin every (k, pair) into its (out-bucket, k) key.
// record = im (18b) | (om & 127) << 18   -- 25 bits, fits one dword.
// ---------------------------------------------------------------------------
__global__ __launch_bounds__(256) void scatter_kernel(
    const int* __restrict__ in_map,
    const int* __restrict__ out_map,
    int*       __restrict__ cnt,
    unsigned int* __restrict__ recs)
{
    const int k = blockIdx.y;
    const int m = blockIdx.x * 256 + threadIdx.x;
    const size_t p = (size_t)k * MPAIR + m;
    const int om = out_map[p];
    const int im = in_map[p];
    const int key = (om >> 7) * KOFF + k;
    const int pos = atomicAdd(&cnt[key], 1);
    if (pos < SLOTS)
        recs[(size_t)key * SLOTS + pos] =
            (unsigned int)im | ((unsigned int)(om & 127) << 18);
}

// ---------------------------------------------------------------------------
// Phase 2: one block per bucket (128 output rows). Waves stripe over k.
// LANE = RECORD: each lane vector-loads ITS OWN feats row into 64 VGPRs
// (16x dwordx4, deep MLP, L1 reuse). The wave-uniform operand is W's column
// (tiny, L2-hot) -> scalar s_loads with K$ reuse. Per co: 64 v_fmac(sgpr) +
// one ds_add into a TRANSPOSED tile[co][row] (banks spread by row). Out
// written once, stats fused.
// ---------------------------------------------------------------------------
__global__ __launch_bounds__(256, 4) void conv_merge_kernel(
    const float* __restrict__ feats,
    const float* __restrict__ WT,
    const int*   __restrict__ cnt,
    const unsigned int* __restrict__ recs,
    float*       __restrict__ out,
    float*       __restrict__ stats)
{
    const int bucket = blockIdx.x;
    const int lane = threadIdx.x & 63;
    const int wave = threadIdx.x >> 6;

    __shared__ __align__(16) float tile[64 * TS + 64];   // 33.3 KB (+dump row)
    __shared__ __align__(16) float4 sred[4][32];         // 2 KB stats partials

    // zero tile (incl. dump)
    {
        float4* tp = (float4*)tile;
        const int n4 = (64 * TS + 64) / 4;               // 2080
        for (int i = threadIdx.x; i < n4; i += 256)
            tp[i] = make_float4(0.f, 0.f, 0.f, 0.f);
    }

    // Prefetch this wave's cnt values: lane j holds cnt of key (wave + 4*j).
    int myn = 0;
    if (lane < 7) {
        const int kk = wave + 4 * lane;
        if (kk < KOFF) myn = cnt[bucket * KOFF + kk];
    }
    __syncthreads();

    const int nkeys = (KOFF - wave + 3) >> 2;

    for (int j = 0; j < nkeys; ++j) {
        const int k = __builtin_amdgcn_readfirstlane(wave + 4 * j);
        int n = __builtin_amdgcn_readlane(myn, j);
        n = n > SLOTS ? SLOTS : n;
        if (n == 0) continue;

        const unsigned int* rbase = recs + (size_t)(bucket * KOFF + k) * SLOTS;
        const float4* wbase = (const float4*)(WT + (size_t)k * C * C);

        const int nbatch = (n + 63) >> 6;
        for (int b = 0; b < nbatch; ++b) {
            const int idx = b * 64 + lane;
            const bool active = idx < n;
            const int idxc = active ? idx : n - 1;

            const unsigned int rec = rbase[idxc];         // coalesced vector load
            const int im  = (int)(rec & 0x3FFFFu);        // per-lane
            const int row = (int)(rec >> 18);              // per-lane, 0..127

            // Per-lane row load: 16 independent dwordx4 (64 VGPRs).
            float4 R[16];
            {
                const float4* fr = (const float4*)(feats + (size_t)im * C);
                #pragma unroll
                for (int i4 = 0; i4 < 16; ++i4) R[i4] = fr[i4];
            }

            // tile address walk: active lanes -> tile[co][row]; inactive ->
            // private dump slot (no same-address serialization).
            int addr = active ? row : (DUMP + lane);
            const int step = active ? TS : 0;

            #pragma unroll 1
            for (int co = 0; co < 64; ++co) {
                const float4* wc = wbase + (size_t)co * 16;   // uniform -> s_load
                float a0 = 0.f, a1 = 0.f, a2 = 0.f, a3 = 0.f;
                #pragma unroll
                for (int i4 = 0; i4 < 16; ++i4) {
                    const float4 w4 = wc[i4];                 // SGPR operand
                    const float4 r4 = R[i4];
                    a0 = fmaf(r4.x, w4.x, a0);
                    a1 = fmaf(r4.y, w4.y, a1);
                    a2 = fmaf(r4.z, w4.z, a2);
                    a3 = fmaf(r4.w, w4.w, a3);
                }
                atomicAdd(&tile[addr], (a0 + a1) + (a2 + a3));  // ds_add_f32
                addr += step;
            }
        }
    }
    __syncthreads();

    // tile[co][row] -> out[row][co] (coalesced), fused per-channel stats.
    const int c0   = (threadIdx.x & 15) * 4;   // channel group
    const int rowg = threadIdx.x >> 4;         // rows rowg, rowg+16, ...
    float4 s = make_float4(0.f, 0.f, 0.f, 0.f);
    float4 q = make_float4(0.f, 0.f, 0.f, 0.f);
    #pragma unroll
    for (int jr = 0; jr < 8; ++jr) {
        const int row = rowg + jr * 16;
        float4 v = make_float4(tile[(c0 + 0) * TS + row],
                               tile[(c0 + 1) * TS + row],
                               tile[(c0 + 2) * TS + row],
                               tile[(c0 + 3) * TS + row]);
        *(float4*)&out[(size_t)bucket * (BROWS * C) + (size_t)row * C + c0] = v;
        s.x += v.x; s.y += v.y; s.z += v.z; s.w += v.w;
        q.x = fmaf(v.x, v.x, q.x); q.y = fmaf(v.y, v.y, q.y);
        q.z = fmaf(v.z, v.z, q.z); q.w = fmaf(v.w, v.w, q.w);
    }

    // wave-level reduce: lanes with equal (lane&15) share a channel group.
    #define RED4(v) do { \
        v.x += __shfl_xor(v.x, 16); v.y += __shfl_xor(v.y, 16); \
        v.z += __shfl_xor(v.z, 16); v.w += __shfl_xor(v.w, 16); \
        v.x += __shfl_xor(v.x, 32); v.y += __shfl_xor(v.y, 32); \
        v.z += __shfl_xor(v.z, 32); v.w += __shfl_xor(v.w, 32); \
    } while (0)
    RED4(s); RED4(q);
    #undef RED4
    if (lane < 16) { sred[wave][lane] = s; sred[wave][16 + lane] = q; }
    __syncthreads();

    if (threadIdx.x < 16) {
        float4 ts = make_float4(0.f, 0.f, 0.f, 0.f);
        float4 tq = make_float4(0.f, 0.f, 0.f, 0.f);
        #pragma unroll
        for (int w = 0; w < 4; ++w) {
            float4 a = sred[w][threadIdx.x];
            float4 b = sred[w][16 + threadIdx.x];
            ts.x += a.x; ts.y += a.y; ts.z += a.z; ts.w += a.w;
            tq.x += b.x; tq.y += b.y; tq.z += b.z; tq.w += b.w;
        }
        const int cc = threadIdx.x * 4;
        unsafeAtomicAdd(&stats[cc + 0], ts.x);
        unsafeAtomicAdd(&stats[cc + 1], ts.y);
        unsafeAtomicAdd(&stats[cc + 2], ts.z);
        unsafeAtomicAdd(&stats[cc + 3], ts.w);
        unsafeAtomicAdd(&stats[64 + cc + 0], tq.x);
        unsafeAtomicAdd(&stats[64 + cc + 1], tq.y);
        unsafeAtomicAdd(&stats[64 + cc + 2], tq.z);
        unsafeAtomicAdd(&stats[64 + cc + 3], tq.w);
    }
}

// ---------------------------------------------------------------------------
// LEGACY PATH (fallback if workspace too small): verified kernels.
// ---------------------------------------------------------------------------
__global__ __launch_bounds__(256) void conv_kernel(
    const float* __restrict__ feats,
    const float* __restrict__ W,
    const int*   __restrict__ in_map,
    const int*   __restrict__ out_map,
    float*       __restrict__ out)
{
    const int k    = blockIdx.y;
    const int lane = threadIdx.x & 63;
    const int wave = threadIdx.x >> 6;

    __shared__ float4 fr4[4][2][16];

    float wreg[C];
    const float* Wk = W + (size_t)k * C * C;
    #pragma unroll
    for (int i = 0; i < C; ++i) wreg[i] = Wk[i * C + lane];

    const int pair_base = (blockIdx.x * 4 + wave) * 64;
    const int my_pair   = pair_base + lane;
    const int my_im = in_map[(size_t)k * MPAIR + my_pair];
    const int my_om = out_map[(size_t)k * MPAIR + my_pair];

    int im0 = __builtin_amdgcn_readlane(my_im, 0);
    float fcur = feats[(size_t)im0 * C + lane];

    for (int p = 0; p < 64; ++p) {
        const int om  = __builtin_amdgcn_readlane(my_om, p);
        const int buf = p & 1;

        ((float*)&fr4[wave][buf][0])[lane] = fcur;

        if (p < 63) {
            int imn = __builtin_amdgcn_readlane(my_im, p + 1);
            fcur = feats[(size_t)imn * C + lane];
        }

        float acc = 0.f;
        #pragma unroll
        for (int j = 0; j < 16; ++j) {
            float4 f = fr4[wave][buf][j];
            acc = fmaf(f.x, wreg[4*j+0], acc);
            acc = fmaf(f.y, wreg[4*j+1], acc);
            acc = fmaf(f.z, wreg[4*j+2], acc);
            acc = fmaf(f.w, wreg[4*j+3], acc);
        }
        unsafeAtomicAdd(&out[(size_t)om * C + lane], acc);
    }
}

__global__ __launch_bounds__(256) void stats_kernel(
    const float* __restrict__ out, float* __restrict__ stats)
{
    __shared__ float4 s_sum[256], s_sq[256];
    const int col4 = threadIdx.x & 15;
    const int rowg = threadIdx.x >> 4;

    float4 s = make_float4(0.f, 0.f, 0.f, 0.f);
    float4 q = make_float4(0.f, 0.f, 0.f, 0.f);
    for (int row = blockIdx.x * 16 + rowg; row < N_OUT; row += gridDim.x * 16) {
        float4 v = *(const float4*)(out + (size_t)row * C + col4 * 4);
        s.x += v.x; s.y += v.y; s.z += v.z; s.w += v.w;
        q.x = fmaf(v.x, v.x, q.x); q.y = fmaf(v.y, v.y, q.y);
        q.z = fmaf(v.z, v.z, q.z); q.w = fmaf(v.w, v.w, q.w);
    }
    s_sum[threadIdx.x] = s; s_sq[threadIdx.x] = q;
    __syncthreads();

    if (threadIdx.x < 16) {
        float4 ts = make_float4(0.f, 0.f, 0.f, 0.f);
        float4 tq = make_float4(0.f, 0.f, 0.f, 0.f);
        for (int j = 0; j < 16; ++j) {
            float4 a = s_sum[j * 16 + threadIdx.x];
            float4 b = s_sq [j * 16 + threadIdx.x];
            ts.x += a.x; ts.y += a.y; ts.z += a.z; ts.w += a.w;
            tq.x += b.x; tq.y += b.y; tq.z += b.z; tq.w += b.w;
        }
        const int c0 = threadIdx.x * 4;
        unsafeAtomicAdd(&stats[c0 + 0], ts.x);
        unsafeAtomicAdd(&stats[c0 + 1], ts.y);
        unsafeAtomicAdd(&stats[c0 + 2], ts.z);
        unsafeAtomicAdd(&stats[c0 + 3], ts.w);
        unsafeAtomicAdd(&stats[64 + c0 + 0], tq.x);
        unsafeAtomicAdd(&stats[64 + c0 + 1], tq.y);
        unsafeAtomicAdd(&stats[64 + c0 + 2], tq.z);
        unsafeAtomicAdd(&stats[64 + c0 + 3], tq.w);
    }
}

// ---------------------------------------------------------------------------
// In-place BN (affine) + LeakyReLU (shared by both paths).
// ---------------------------------------------------------------------------
__global__ __launch_bounds__(256) void bn_kernel(
    float* __restrict__ out,
    const float* __restrict__ stats,
    const float* __restrict__ gamma,
    const float* __restrict__ beta)
{
    __shared__ __align__(16) float s_scale[C];
    __shared__ __align__(16) float s_shift[C];
    if (threadIdx.x < C) {
        const float inv_n = 1.0f / (float)N_OUT;
        float mean = stats[threadIdx.x] * inv_n;
        float var  = stats[C + threadIdx.x] * inv_n - mean * mean;
        float sc   = gamma[threadIdx.x] * rsqrtf(var + EPS);
        s_scale[threadIdx.x] = sc;
        s_shift[threadIdx.x] = beta[threadIdx.x] - mean * sc;
    }
    __syncthreads();

    const int col4 = threadIdx.x & 15;
    const int rowg = threadIdx.x >> 4;
    const float4 sc4 = *(const float4*)&s_scale[col4 * 4];
    const float4 sh4 = *(const float4*)&s_shift[col4 * 4];

    for (int row = blockIdx.x * 16 + rowg; row < N_OUT; row += gridDim.x * 16) {
        float4* p = (float4*)(out + (size_t)row * C + col4 * 4);
        float4 v = *p;
        v.x = fmaf(v.x, sc4.x, sh4.x);
        v.y = fmaf(v.y, sc4.y, sh4.y);
        v.z = fmaf(v.z, sc4.z, sh4.z);
        v.w = fmaf(v.w, sc4.w, sh4.w);
        v.x = v.x >= 0.f ? v.x : NEG_SLOPE * v.x;
        v.y = v.y >= 0.f ? v.y : NEG_SLOPE * v.y;
        v.z = v.z >= 0.f ? v.z : NEG_SLOPE * v.z;
        v.w = v.w >= 0.f ? v.w : NEG_SLOPE * v.w;
        *p = v;
    }
}

extern "C" void kernel_launch(void* const* d_in, const int* in_sizes, int n_in,
                              void* d_out, int out_size, void* d_ws, size_t ws_size,
                              hipStream_t stream) {
    const float* feats  = (const float*)d_in[0];
    const float* W      = (const float*)d_in[1];
    const float* gamma  = (const float*)d_in[2];
    const float* beta   = (const float*)d_in[3];
    const int*  in_map  = (const int*)d_in[4];
    const int*  out_map = (const int*)d_in[5];
    // d_in[6] = num_out (known constant N_OUT)

    float* out   = (float*)d_out;
    float* stats = (float*)d_ws;                       // 128 floats @ offset 0

    const size_t CNT_OFF = 1024;
    const size_t REC_OFF = CNT_OFF + (size_t)NKEY * 4;
    const size_t WT_OFF  = REC_OFF + ((size_t)NKEY * SLOTS + 128) * 4;
    const size_t NEEDED  = WT_OFF + (size_t)KOFF * C * C * 4;   // ~29 MB

    if (ws_size >= NEEDED) {
        // --- bucketed-merge path: lane-per-record conv, no global fp atomics ---
        int* cnt = (int*)((char*)d_ws + CNT_OFF);
        unsigned int* recs = (unsigned int*)((char*)d_ws + REC_OFF);
        float* WT = (float*)((char*)d_ws + WT_OFF);

        hipMemsetAsync(stats, 0, 2 * C * sizeof(float), stream);
        hipMemsetAsync(cnt, 0, (size_t)NKEY * sizeof(int), stream);
        // NOTE: no memset of out -- conv_merge fully overwrites every row.

        wt_kernel<<<KOFF, 256, 0, stream>>>(W, WT);
        dim3 sgrid(MPAIR / 256, KOFF);
        scatter_kernel<<<sgrid, 256, 0, stream>>>(in_map, out_map, cnt, recs);
        conv_merge_kernel<<<NBUCKET, 256, 0, stream>>>(feats, WT, cnt, recs, out, stats);
        bn_kernel<<<512, 256, 0, stream>>>(out, stats, gamma, beta);
    } else {
        // --- legacy path (verified): atomic scatter + separate stats ---
        hipMemsetAsync(out, 0, (size_t)N_OUT * C * sizeof(float), stream);
        hipMemsetAsync(stats, 0, 2 * C * sizeof(float), stream);

        dim3 cgrid(MPAIR / 256, KOFF);
        conv_kernel<<<cgrid, 256, 0, stream>>>(feats, W, in_map, out_map, out);
        stats_kernel<<<256, 256, 0, stream>>>(out, stats);
        bn_kernel<<<512, 256, 0, stream>>>(out, stats, gamma, beta);
    }
}

// Round 6
// 1804.367 us; speedup vs baseline: 1.1777x; 1.1777x over previous
//
#include <hip/hip_runtime.h>

#define N_IN   262144
#define N_OUT  262144
#define KOFF   27
#define MPAIR  131072
#define C      64
#define EPS    1e-5f
#define NEG_SLOPE 0.01f

// ---- bucketed-merge parameters -------------------------------------------
#define BROWS   64                    // output rows per bucket
#define NBUCKET (N_OUT / BROWS)       // 4096
#define NKEY    (NBUCKET * KOFF)      // 110592 (bucket-major, k minor)
#define SLOTS   80                    // per-key cap; lambda=32, P(ovfl)~4e-12
#define TS      65                    // tile row stride (pad -> banks spread)
#define DUMP    (BROWS * TS)          // dump slots for padded lanes
#define TSZ     (DUMP + 128)          // 4288 floats = 16.75 KB

typedef _Float16 half4 __attribute__((ext_vector_type(4)));
typedef float    f32x4 __attribute__((ext_vector_type(4)));

// ---------------------------------------------------------------------------
// Phase 0: W[k][cin][cout] -> fragment-ready fp16 layout.
// w16[k][t=kt*4+nt][lane] = half4{ W[k][kt*16+4*(lane>>4)+e][nt*16+(lane&15)] }
// (B-frag of v_mfma_f32_16x16x16_f16: lane l holds B[4*(l/16)+e][l%16].)
// ---------------------------------------------------------------------------
__global__ __launch_bounds__(256) void w16_kernel(
    const float* __restrict__ W, half4* __restrict__ w16)
{
    const int k    = blockIdx.x;
    const int lane = threadIdx.x & 63;
    const int q    = threadIdx.x >> 6;
    for (int t = q; t < 16; t += 4) {
        const int kt = t >> 2, nt = t & 3;
        const int cin  = kt * 16 + ((lane >> 4) << 2);
        const int cout = nt * 16 + (lane & 15);
        const float* src = W + ((size_t)k * C + cin) * C + cout;
        half4 h;
        h.x = (_Float16)src[0 * C];
        h.y = (_Float16)src[1 * C];
        h.z = (_Float16)src[2 * C];
        h.w = (_Float16)src[3 * C];
        w16[((size_t)k * 16 + t) * 64 + lane] = h;
    }
}

// ---------------------------------------------------------------------------
// Phase 1: bin every (k, pair) into its (out-bucket, k) key.
// record = im (18b) | (om & 63) << 18
// ---------------------------------------------------------------------------
__global__ __launch_bounds__(256) void scatter_kernel(
    const int* __restrict__ in_map,
    const int* __restrict__ out_map,
    int*       __restrict__ cnt,
    unsigned int* __restrict__ recs)
{
    const int k = blockIdx.y;
    const int m = blockIdx.x * 256 + threadIdx.x;
    const size_t p = (size_t)k * MPAIR + m;
    const int om = out_map[p];
    const int im = in_map[p];
    const int key = (om >> 6) * KOFF + k;
    const int pos = atomicAdd(&cnt[key], 1);
    if (pos < SLOTS)
        recs[(size_t)key * SLOTS + pos] =
            (unsigned int)im | ((unsigned int)(om & 63) << 18);
}

// ---------------------------------------------------------------------------
// Phase 2: one block per bucket (64 rows). Waves stripe over k. Per key:
// B-frags (W, fp16) register-resident; per 16-record group: 4 A-frags loaded
// straight from global feats (per-lane addresses, fp32->fp16 casts), 16x
// v_mfma_f32_16x16x16_f16 (fp32 acc), scatter via 16 ds_add into a stride-65
// LDS tile. One-group-deep software pipeline on rec+A loads. Out written
// once; per-channel stats fused.
// ---------------------------------------------------------------------------
__global__ __launch_bounds__(256, 4) void conv_mfma_kernel(
    const float* __restrict__ feats,
    const half4* __restrict__ w16,
    const int*   __restrict__ cnt,
    const unsigned int* __restrict__ recs,
    float*       __restrict__ out,
    float*       __restrict__ stats)
{
    const int bucket = blockIdx.x;
    const int lane = threadIdx.x & 63;
    const int wave = threadIdx.x >> 6;
    const int mrow = lane & 15;          // A-side record slot / D col
    const int krow = (lane >> 4) << 2;   // k offset within 16-k tile / D row grp

    __shared__ float tile[TSZ];
    __shared__ __align__(16) float4 sred[4][32];

    for (int i = threadIdx.x; i < TSZ / 4; i += 256)
        ((float4*)tile)[i] = make_float4(0.f, 0.f, 0.f, 0.f);

    int myn = 0;
    if (lane < 7) {
        const int kk = wave + 4 * lane;
        if (kk < KOFF) myn = cnt[bucket * KOFF + kk];
    }
    __syncthreads();

    const int nkeys = (KOFF - wave + 3) >> 2;
    for (int j = 0; j < nkeys; ++j) {
        const int k = wave + 4 * j;
        int n = __builtin_amdgcn_readlane(myn, j);
        n = n > SLOTS ? SLOTS : n;
        if (n == 0) continue;

        const unsigned int* rbase = recs + (size_t)(bucket * KOFF + k) * SLOTS;

        // Register-resident B fragments: bf[kt][nt]
        half4 bf[4][4];
        {
            const half4* wb = w16 + ((size_t)k * 16) * 64 + lane;
            #pragma unroll
            for (int kt = 0; kt < 4; ++kt)
                #pragma unroll
                for (int nt = 0; nt < 4; ++nt)
                    bf[kt][nt] = wb[(kt * 4 + nt) * 64];
        }

        const int ng = (n + 15) >> 4;

        // pipeline prologue: records + A loads for group 0 (garbage slots are
        // in-bounds: im is 18-bit -> [0, N_IN); zeroed before use)
        unsigned int recC = rbase[mrow];
        unsigned int recN = (ng > 1) ? rbase[16 + mrow] : recC;
        float4 fa0, fa1, fa2, fa3;
        {
            const float* fr = feats + ((size_t)(recC & 0x3FFFFu)) * C + krow;
            fa0 = *(const float4*)(fr);
            fa1 = *(const float4*)(fr + 16);
            fa2 = *(const float4*)(fr + 32);
            fa3 = *(const float4*)(fr + 48);
        }

        for (int g = 0; g < ng; ++g) {
            unsigned int recN2 = recN;
            if (g + 2 < ng) recN2 = rbase[(g + 2) * 16 + mrow];

            // convert current A-frags; zero padded record slots (select, not
            // multiply: garbage bits may be NaN)
            const bool vA = (g * 16 + mrow) < n;
            half4 az0, az1, az2, az3;
            {
                az0.x = (_Float16)fa0.x; az0.y = (_Float16)fa0.y;
                az0.z = (_Float16)fa0.z; az0.w = (_Float16)fa0.w;
                az1.x = (_Float16)fa1.x; az1.y = (_Float16)fa1.y;
                az1.z = (_Float16)fa1.z; az1.w = (_Float16)fa1.w;
                az2.x = (_Float16)fa2.x; az2.y = (_Float16)fa2.y;
                az2.z = (_Float16)fa2.z; az2.w = (_Float16)fa2.w;
                az3.x = (_Float16)fa3.x; az3.y = (_Float16)fa3.y;
                az3.z = (_Float16)fa3.z; az3.w = (_Float16)fa3.w;
                if (!vA) {
                    const half4 hz = {(_Float16)0.f, (_Float16)0.f,
                                      (_Float16)0.f, (_Float16)0.f};
                    az0 = hz; az1 = hz; az2 = hz; az3 = hz;
                }
            }

            // issue next group's A loads (latency hides under MFMA+scatter)
            float4 fb0 = fa0, fb1 = fa1, fb2 = fa2, fb3 = fa3;
            if (g + 1 < ng) {
                const float* frn = feats + ((size_t)(recN & 0x3FFFFu)) * C + krow;
                fb0 = *(const float4*)(frn);
                fb1 = *(const float4*)(frn + 16);
                fb2 = *(const float4*)(frn + 32);
                fb3 = *(const float4*)(frn + 48);
            }

            // 16 MFMAs: D[m=record][n=cout], fp32 accumulate
            f32x4 ac0 = {0.f,0.f,0.f,0.f}, ac1 = {0.f,0.f,0.f,0.f};
            f32x4 ac2 = {0.f,0.f,0.f,0.f}, ac3 = {0.f,0.f,0.f,0.f};
            #pragma unroll
            for (int kt = 0; kt < 4; ++kt) {
                const half4 a = (kt == 0) ? az0 : (kt == 1) ? az1
                              : (kt == 2) ? az2 : az3;
                ac0 = __builtin_amdgcn_mfma_f32_16x16x16f16(a, bf[kt][0], ac0, 0, 0, 0);
                ac1 = __builtin_amdgcn_mfma_f32_16x16x16f16(a, bf[kt][1], ac1, 0, 0, 0);
                ac2 = __builtin_amdgcn_mfma_f32_16x16x16f16(a, bf[kt][2], ac2, 0, 0, 0);
                ac3 = __builtin_amdgcn_mfma_f32_16x16x16f16(a, bf[kt][3], ac3, 0, 0, 0);
            }

            // scatter: lane holds D[krow+r][mrow + nt*16]
            #pragma unroll
            for (int r = 0; r < 4; ++r) {
                const int jj = krow + r;                       // record in group
                const unsigned int rj = (unsigned int)__shfl((int)recC, jj);
                const int idx2 = g * 16 + jj;
                float* tp = (idx2 < n)
                          ? &tile[(int)(rj >> 18) * TS + mrow]
                          : &tile[DUMP + lane];
                atomicAdd(tp +  0, ac0[r]);
                atomicAdd(tp + 16, ac1[r]);
                atomicAdd(tp + 32, ac2[r]);
                atomicAdd(tp + 48, ac3[r]);
            }

            recC = recN; recN = recN2;
            fa0 = fb0; fa1 = fb1; fa2 = fb2; fa3 = fb3;
        }
    }
    __syncthreads();

    // tile -> out (coalesced), fused per-channel sum / sumsq.
    const int c0   = (threadIdx.x & 15) * 4;
    const int rowg = threadIdx.x >> 4;
    float4 s = make_float4(0.f, 0.f, 0.f, 0.f);
    float4 q = make_float4(0.f, 0.f, 0.f, 0.f);
    #pragma unroll
    for (int jr = 0; jr < 4; ++jr) {
        const int row = rowg + jr * 16;
        float4 v = make_float4(tile[row * TS + c0 + 0],
                               tile[row * TS + c0 + 1],
                               tile[row * TS + c0 + 2],
                               tile[row * TS + c0 + 3]);
        *(float4*)&out[(size_t)bucket * (BROWS * C) + (size_t)row * C + c0] = v;
        s.x += v.x; s.y += v.y; s.z += v.z; s.w += v.w;
        q.x = fmaf(v.x, v.x, q.x); q.y = fmaf(v.y, v.y, q.y);
        q.z = fmaf(v.z, v.z, q.z); q.w = fmaf(v.w, v.w, q.w);
    }
    #define RED4(v) do { \
        v.x += __shfl_xor(v.x, 16); v.y += __shfl_xor(v.y, 16); \
        v.z += __shfl_xor(v.z, 16); v.w += __shfl_xor(v.w, 16); \
        v.x += __shfl_xor(v.x, 32); v.y += __shfl_xor(v.y, 32); \
        v.z += __shfl_xor(v.z, 32); v.w += __shfl_xor(v.w, 32); \
    } while (0)
    RED4(s); RED4(q);
    #undef RED4
    if (lane < 16) { sred[wave][lane] = s; sred[wave][16 + lane] = q; }
    __syncthreads();

    if (threadIdx.x < 16) {
        float4 ts = make_float4(0.f, 0.f, 0.f, 0.f);
        float4 tq = make_float4(0.f, 0.f, 0.f, 0.f);
        #pragma unroll
        for (int w = 0; w < 4; ++w) {
            float4 a = sred[w][threadIdx.x];
            float4 b = sred[w][16 + threadIdx.x];
            ts.x += a.x; ts.y += a.y; ts.z += a.z; ts.w += a.w;
            tq.x += b.x; tq.y += b.y; tq.z += b.z; tq.w += b.w;
        }
        const int cc = threadIdx.x * 4;
        unsafeAtomicAdd(&stats[cc + 0], ts.x);
        unsafeAtomicAdd(&stats[cc + 1], ts.y);
        unsafeAtomicAdd(&stats[cc + 2], ts.z);
        unsafeAtomicAdd(&stats[cc + 3], ts.w);
        unsafeAtomicAdd(&stats[64 + cc + 0], tq.x);
        unsafeAtomicAdd(&stats[64 + cc + 1], tq.y);
        unsafeAtomicAdd(&stats[64 + cc + 2], tq.z);
        unsafeAtomicAdd(&stats[64 + cc + 3], tq.w);
    }
}

// ---------------------------------------------------------------------------
// LEGACY PATH (fallback if workspace too small): verified kernels.
// ---------------------------------------------------------------------------
__global__ __launch_bounds__(256) void conv_kernel(
    const float* __restrict__ feats,
    const float* __restrict__ W,
    const int*   __restrict__ in_map,
    const int*   __restrict__ out_map,
    float*       __restrict__ out)
{
    const int k    = blockIdx.y;
    const int lane = threadIdx.x & 63;
    const int wave = threadIdx.x >> 6;

    __shared__ float4 fr4[4][2][16];

    float wreg[C];
    const float* Wk = W + (size_t)k * C * C;
    #pragma unroll
    for (int i = 0; i < C; ++i) wreg[i] = Wk[i * C + lane];

    const int pair_base = (blockIdx.x * 4 + wave) * 64;
    const int my_pair   = pair_base + lane;
    const int my_im = in_map[(size_t)k * MPAIR + my_pair];
    const int my_om = out_map[(size_t)k * MPAIR + my_pair];

    int im0 = __builtin_amdgcn_readlane(my_im, 0);
    float fcur = feats[(size_t)im0 * C + lane];

    for (int p = 0; p < 64; ++p) {
        const int om  = __builtin_amdgcn_readlane(my_om, p);
        const int buf = p & 1;

        ((float*)&fr4[wave][buf][0])[lane] = fcur;

        if (p < 63) {
            int imn = __builtin_amdgcn_readlane(my_im, p + 1);
            fcur = feats[(size_t)imn * C + lane];
        }

        float acc = 0.f;
        #pragma unroll
        for (int jq = 0; jq < 16; ++jq) {
            float4 f = fr4[wave][buf][jq];
            acc = fmaf(f.x, wreg[4*jq+0], acc);
            acc = fmaf(f.y, wreg[4*jq+1], acc);
            acc = fmaf(f.z, wreg[4*jq+2], acc);
            acc = fmaf(f.w, wreg[4*jq+3], acc);
        }
        unsafeAtomicAdd(&out[(size_t)om * C + lane], acc);
    }
}

__global__ __launch_bounds__(256) void stats_kernel(
    const float* __restrict__ out, float* __restrict__ stats)
{
    __shared__ float4 s_sum[256], s_sq[256];
    const int col4 = threadIdx.x & 15;
    const int rowg = threadIdx.x >> 4;

    float4 s = make_float4(0.f, 0.f, 0.f, 0.f);
    float4 q = make_float4(0.f, 0.f, 0.f, 0.f);
    for (int row = blockIdx.x * 16 + rowg; row < N_OUT; row += gridDim.x * 16) {
        float4 v = *(const float4*)(out + (size_t)row * C + col4 * 4);
        s.x += v.x; s.y += v.y; s.z += v.z; s.w += v.w;
        q.x = fmaf(v.x, v.x, q.x); q.y = fmaf(v.y, v.y, q.y);
        q.z = fmaf(v.z, v.z, q.z); q.w = fmaf(v.w, v.w, q.w);
    }
    s_sum[threadIdx.x] = s; s_sq[threadIdx.x] = q;
    __syncthreads();

    if (threadIdx.x < 16) {
        float4 ts = make_float4(0.f, 0.f, 0.f, 0.f);
        float4 tq = make_float4(0.f, 0.f, 0.f, 0.f);
        for (int jq = 0; jq < 16; ++jq) {
            float4 a = s_sum[jq * 16 + threadIdx.x];
            float4 b = s_sq [jq * 16 + threadIdx.x];
            ts.x += a.x; ts.y += a.y; ts.z += a.z; ts.w += a.w;
            tq.x += b.x; tq.y += b.y; tq.z += b.z; tq.w += b.w;
        }
        const int c0 = threadIdx.x * 4;
        unsafeAtomicAdd(&stats[c0 + 0], ts.x);
        unsafeAtomicAdd(&stats[c0 + 1], ts.y);
        unsafeAtomicAdd(&stats[c0 + 2], ts.z);
        unsafeAtomicAdd(&stats[c0 + 3], ts.w);
        unsafeAtomicAdd(&stats[64 + c0 + 0], tq.x);
        unsafeAtomicAdd(&stats[64 + c0 + 1], tq.y);
        unsafeAtomicAdd(&stats[64 + c0 + 2], tq.z);
        unsafeAtomicAdd(&stats[64 + c0 + 3], tq.w);
    }
}

// ---------------------------------------------------------------------------
// In-place BN (affine) + LeakyReLU (shared by both paths).
// ---------------------------------------------------------------------------
__global__ __launch_bounds__(256) void bn_kernel(
    float* __restrict__ out,
    const float* __restrict__ stats,
    const float* __restrict__ gamma,
    const float* __restrict__ beta)
{
    __shared__ __align__(16) float s_scale[C];
    __shared__ __align__(16) float s_shift[C];
    if (threadIdx.x < C) {
        const float inv_n = 1.0f / (float)N_OUT;
        float mean = stats[threadIdx.x] * inv_n;
        float var  = stats[C + threadIdx.x] * inv_n - mean * mean;
        float sc   = gamma[threadIdx.x] * rsqrtf(var + EPS);
        s_scale[threadIdx.x] = sc;
        s_shift[threadIdx.x] = beta[threadIdx.x] - mean * sc;
    }
    __syncthreads();

    const int col4 = threadIdx.x & 15;
    const int rowg = threadIdx.x >> 4;
    const float4 sc4 = *(const float4*)&s_scale[col4 * 4];
    const float4 sh4 = *(const float4*)&s_shift[col4 * 4];

    for (int row = blockIdx.x * 16 + rowg; row < N_OUT; row += gridDim.x * 16) {
        float4* p = (float4*)(out + (size_t)row * C + col4 * 4);
        float4 v = *p;
        v.x = fmaf(v.x, sc4.x, sh4.x);
        v.y = fmaf(v.y, sc4.y, sh4.y);
        v.z = fmaf(v.z, sc4.z, sh4.z);
        v.w = fmaf(v.w, sc4.w, sh4.w);
        v.x = v.x >= 0.f ? v.x : NEG_SLOPE * v.x;
        v.y = v.y >= 0.f ? v.y : NEG_SLOPE * v.y;
        v.z = v.z >= 0.f ? v.z : NEG_SLOPE * v.z;
        v.w = v.w >= 0.f ? v.w : NEG_SLOPE * v.w;
        *p = v;
    }
}

extern "C" void kernel_launch(void* const* d_in, const int* in_sizes, int n_in,
                              void* d_out, int out_size, void* d_ws, size_t ws_size,
                              hipStream_t stream) {
    const float* feats  = (const float*)d_in[0];
    const float* W      = (const float*)d_in[1];
    const float* gamma  = (const float*)d_in[2];
    const float* beta   = (const float*)d_in[3];
    const int*  in_map  = (const int*)d_in[4];
    const int*  out_map = (const int*)d_in[5];
    // d_in[6] = num_out (known constant N_OUT)

    float* out   = (float*)d_out;
    float* stats = (float*)d_ws;                       // 128 floats @ offset 0

    const size_t CNT_OFF = 1024;
    const size_t REC_OFF = CNT_OFF + (size_t)NKEY * 4;                  // 443392
    const size_t W16_OFF = REC_OFF + (size_t)NKEY * SLOTS * 4;          // +35.4 MB
    const size_t NEEDED  = W16_OFF + (size_t)KOFF * 16 * 64 * 8 + 1024; // ~36.1 MB

    if (ws_size >= NEEDED) {
        // --- bucketed MFMA path: matrix pipe, no global fp atomics ---
        int* cnt = (int*)((char*)d_ws + CNT_OFF);
        unsigned int* recs = (unsigned int*)((char*)d_ws + REC_OFF);
        half4* w16 = (half4*)((char*)d_ws + W16_OFF);

        hipMemsetAsync(stats, 0, 2 * C * sizeof(float), stream);
        hipMemsetAsync(cnt, 0, (size_t)NKEY * sizeof(int), stream);
        // NOTE: no memset of out -- conv_mfma fully overwrites every row.

        w16_kernel<<<KOFF, 256, 0, stream>>>(W, w16);
        dim3 sgrid(MPAIR / 256, KOFF);
        scatter_kernel<<<sgrid, 256, 0, stream>>>(in_map, out_map, cnt, recs);
        conv_mfma_kernel<<<NBUCKET, 256, 0, stream>>>(feats, w16, cnt, recs, out, stats);
        bn_kernel<<<512, 256, 0, stream>>>(out, stats, gamma, beta);
    } else {
        // --- legacy path (verified): atomic scatter + separate stats ---
        hipMemsetAsync(out, 0, (size_t)N_OUT * C * sizeof(float), stream);
        hipMemsetAsync(stats, 0, 2 * C * sizeof(float), stream);

        dim3 cgrid(MPAIR / 256, KOFF);
        conv_kernel<<<cgrid, 256, 0, stream>>>(feats, W, in_map, out_map, out);
        stats_kernel<<<256, 256, 0, stream>>>(out, stats);
        bn_kernel<<<512, 256, 0, stream>>>(out, stats, gamma, beta);
    }
}

// Round 7
// 1792.120 us; speedup vs baseline: 1.1857x; 1.0068x over previous
//
#include <hip/hip_runtime.h>

#define N_IN   262144
#define N_OUT  262144
#define KOFF   27
#define MPAIR  131072
#define C      64
#define EPS    1e-5f
#define NEG_SLOPE 0.01f

// ---- bucketed-merge parameters -------------------------------------------
#define BROWS   64                    // output rows per bucket
#define NBUCKET (N_OUT / BROWS)       // 4096
#define NKEY    (NBUCKET * KOFF)      // 110592 (bucket-major, k minor)
#define SLOTS   80                    // per-key cap; lambda=32, P(ovfl)~4e-12
#define TS      65                    // tile row stride (pad -> banks spread)
#define DUMP    (BROWS * TS)          // dump slots for padded lanes
#define TSZ     (DUMP + 128)          // 4288 floats = 16.75 KB

typedef _Float16 half4 __attribute__((ext_vector_type(4)));
typedef float    f32x4 __attribute__((ext_vector_type(4)));

// ---------------------------------------------------------------------------
// Phase 0: W[k][cin][cout] -> fragment-ready fp16 layout.
// w16[k][t=kt*4+nt][lane] = half4{ W[k][kt*16+4*(lane>>4)+e][nt*16+(lane&15)] }
// (B-frag of v_mfma_f32_16x16x16_f16: lane l holds B[4*(l/16)+e][l%16].)
// ---------------------------------------------------------------------------
__global__ __launch_bounds__(256) void w16_kernel(
    const float* __restrict__ W, half4* __restrict__ w16)
{
    const int k    = blockIdx.x;
    const int lane = threadIdx.x & 63;
    const int q    = threadIdx.x >> 6;
    for (int t = q; t < 16; t += 4) {
        const int kt = t >> 2, nt = t & 3;
        const int cin  = kt * 16 + ((lane >> 4) << 2);
        const int cout = nt * 16 + (lane & 15);
        const float* src = W + ((size_t)k * C + cin) * C + cout;
        half4 h;
        h.x = (_Float16)src[0 * C];
        h.y = (_Float16)src[1 * C];
        h.z = (_Float16)src[2 * C];
        h.w = (_Float16)src[3 * C];
        w16[((size_t)k * 16 + t) * 64 + lane] = h;
    }
}

// ---------------------------------------------------------------------------
// Phase 1: bin every (k, pair) into its (out-bucket, k) key.
// record = im (18b) | (om & 63) << 18
// ---------------------------------------------------------------------------
__global__ __launch_bounds__(256) void scatter_kernel(
    const int* __restrict__ in_map,
    const int* __restrict__ out_map,
    int*       __restrict__ cnt,
    unsigned int* __restrict__ recs)
{
    const int k = blockIdx.y;
    const int m = blockIdx.x * 256 + threadIdx.x;
    const size_t p = (size_t)k * MPAIR + m;
    const int om = out_map[p];
    const int im = in_map[p];
    const int key = (om >> 6) * KOFF + k;
    const int pos = atomicAdd(&cnt[key], 1);
    if (pos < SLOTS)
        recs[(size_t)key * SLOTS + pos] =
            (unsigned int)im | ((unsigned int)(om & 63) << 18);
}

// ---------------------------------------------------------------------------
// Phase 2: one block per bucket (64 rows). Waves stripe over k. Per key:
// B-frags (W, fp16) register-resident; per 16-record group: 4 A-frags loaded
// straight from global feats (per-lane addresses, fp32->fp16 casts), 16x
// v_mfma_f32_16x16x16_f16 (fp32 acc), scatter via 16 HW ds_add_f32
// (unsafeAtomicAdd -- plain atomicAdd on LDS fp32 is a CAS LOOP, which was
// the hidden serializer of rounds 2/4/6). Out written once; stats fused.
// ---------------------------------------------------------------------------
__global__ __launch_bounds__(256, 4) void conv_mfma_kernel(
    const float* __restrict__ feats,
    const half4* __restrict__ w16,
    const int*   __restrict__ cnt,
    const unsigned int* __restrict__ recs,
    float*       __restrict__ out,
    float*       __restrict__ stats)
{
    const int bucket = blockIdx.x;
    const int lane = threadIdx.x & 63;
    const int wave = threadIdx.x >> 6;
    const int mrow = lane & 15;          // A-side record slot / D col
    const int krow = (lane >> 4) << 2;   // k offset within 16-k tile / D row grp

    __shared__ float tile[TSZ];
    __shared__ __align__(16) float4 sred[4][32];

    for (int i = threadIdx.x; i < TSZ / 4; i += 256)
        ((float4*)tile)[i] = make_float4(0.f, 0.f, 0.f, 0.f);

    int myn = 0;
    if (lane < 7) {
        const int kk = wave + 4 * lane;
        if (kk < KOFF) myn = cnt[bucket * KOFF + kk];
    }
    __syncthreads();

    const int nkeys = (KOFF - wave + 3) >> 2;
    for (int j = 0; j < nkeys; ++j) {
        const int k = wave + 4 * j;
        int n = __builtin_amdgcn_readlane(myn, j);
        n = n > SLOTS ? SLOTS : n;
        if (n == 0) continue;

        const unsigned int* rbase = recs + (size_t)(bucket * KOFF + k) * SLOTS;

        // Register-resident B fragments: bf[kt][nt]
        half4 bf[4][4];
        {
            const half4* wb = w16 + ((size_t)k * 16) * 64 + lane;
            #pragma unroll
            for (int kt = 0; kt < 4; ++kt)
                #pragma unroll
                for (int nt = 0; nt < 4; ++nt)
                    bf[kt][nt] = wb[(kt * 4 + nt) * 64];
        }

        const int ng = (n + 15) >> 4;

        // pipeline prologue: records + A loads for group 0 (garbage slots are
        // in-bounds: im is 18-bit -> [0, N_IN); zeroed before use)
        unsigned int recC = rbase[mrow];
        unsigned int recN = (ng > 1) ? rbase[16 + mrow] : recC;
        float4 fa0, fa1, fa2, fa3;
        {
            const float* fr = feats + ((size_t)(recC & 0x3FFFFu)) * C + krow;
            fa0 = *(const float4*)(fr);
            fa1 = *(const float4*)(fr + 16);
            fa2 = *(const float4*)(fr + 32);
            fa3 = *(const float4*)(fr + 48);
        }

        for (int g = 0; g < ng; ++g) {
            unsigned int recN2 = recN;
            if (g + 2 < ng) recN2 = rbase[(g + 2) * 16 + mrow];

            // convert current A-frags; zero padded record slots (select, not
            // multiply: garbage bits may be NaN)
            const bool vA = (g * 16 + mrow) < n;
            half4 az0, az1, az2, az3;
            {
                az0.x = (_Float16)fa0.x; az0.y = (_Float16)fa0.y;
                az0.z = (_Float16)fa0.z; az0.w = (_Float16)fa0.w;
                az1.x = (_Float16)fa1.x; az1.y = (_Float16)fa1.y;
                az1.z = (_Float16)fa1.z; az1.w = (_Float16)fa1.w;
                az2.x = (_Float16)fa2.x; az2.y = (_Float16)fa2.y;
                az2.z = (_Float16)fa2.z; az2.w = (_Float16)fa2.w;
                az3.x = (_Float16)fa3.x; az3.y = (_Float16)fa3.y;
                az3.z = (_Float16)fa3.z; az3.w = (_Float16)fa3.w;
                if (!vA) {
                    const half4 hz = {(_Float16)0.f, (_Float16)0.f,
                                      (_Float16)0.f, (_Float16)0.f};
                    az0 = hz; az1 = hz; az2 = hz; az3 = hz;
                }
            }

            // issue next group's A loads (latency hides under MFMA+scatter)
            float4 fb0 = fa0, fb1 = fa1, fb2 = fa2, fb3 = fa3;
            if (g + 1 < ng) {
                const float* frn = feats + ((size_t)(recN & 0x3FFFFu)) * C + krow;
                fb0 = *(const float4*)(frn);
                fb1 = *(const float4*)(frn + 16);
                fb2 = *(const float4*)(frn + 32);
                fb3 = *(const float4*)(frn + 48);
            }

            // 16 MFMAs: D[m=record][n=cout], fp32 accumulate
            f32x4 ac0 = {0.f,0.f,0.f,0.f}, ac1 = {0.f,0.f,0.f,0.f};
            f32x4 ac2 = {0.f,0.f,0.f,0.f}, ac3 = {0.f,0.f,0.f,0.f};
            #pragma unroll
            for (int kt = 0; kt < 4; ++kt) {
                const half4 a = (kt == 0) ? az0 : (kt == 1) ? az1
                              : (kt == 2) ? az2 : az3;
                ac0 = __builtin_amdgcn_mfma_f32_16x16x16f16(a, bf[kt][0], ac0, 0, 0, 0);
                ac1 = __builtin_amdgcn_mfma_f32_16x16x16f16(a, bf[kt][1], ac1, 0, 0, 0);
                ac2 = __builtin_amdgcn_mfma_f32_16x16x16f16(a, bf[kt][2], ac2, 0, 0, 0);
                ac3 = __builtin_amdgcn_mfma_f32_16x16x16f16(a, bf[kt][3], ac3, 0, 0, 0);
            }

            // scatter: lane holds D[krow+r][mrow + nt*16]; HW ds_add_f32
            #pragma unroll
            for (int r = 0; r < 4; ++r) {
                const int jj = krow + r;                       // record in group
                const unsigned int rj = (unsigned int)__shfl((int)recC, jj);
                const int idx2 = g * 16 + jj;
                float* tp = (idx2 < n)
                          ? &tile[(int)(rj >> 18) * TS + mrow]
                          : &tile[DUMP + lane];
                unsafeAtomicAdd(tp +  0, ac0[r]);
                unsafeAtomicAdd(tp + 16, ac1[r]);
                unsafeAtomicAdd(tp + 32, ac2[r]);
                unsafeAtomicAdd(tp + 48, ac3[r]);
            }

            recC = recN; recN = recN2;
            fa0 = fb0; fa1 = fb1; fa2 = fb2; fa3 = fb3;
        }
    }
    __syncthreads();

    // tile -> out (coalesced), fused per-channel sum / sumsq.
    const int c0   = (threadIdx.x & 15) * 4;
    const int rowg = threadIdx.x >> 4;
    float4 s = make_float4(0.f, 0.f, 0.f, 0.f);
    float4 q = make_float4(0.f, 0.f, 0.f, 0.f);
    #pragma unroll
    for (int jr = 0; jr < 4; ++jr) {
        const int row = rowg + jr * 16;
        float4 v = make_float4(tile[row * TS + c0 + 0],
                               tile[row * TS + c0 + 1],
                               tile[row * TS + c0 + 2],
                               tile[row * TS + c0 + 3]);
        *(float4*)&out[(size_t)bucket * (BROWS * C) + (size_t)row * C + c0] = v;
        s.x += v.x; s.y += v.y; s.z += v.z; s.w += v.w;
        q.x = fmaf(v.x, v.x, q.x); q.y = fmaf(v.y, v.y, q.y);
        q.z = fmaf(v.z, v.z, q.z); q.w = fmaf(v.w, v.w, q.w);
    }
    #define RED4(v) do { \
        v.x += __shfl_xor(v.x, 16); v.y += __shfl_xor(v.y, 16); \
        v.z += __shfl_xor(v.z, 16); v.w += __shfl_xor(v.w, 16); \
        v.x += __shfl_xor(v.x, 32); v.y += __shfl_xor(v.y, 32); \
        v.z += __shfl_xor(v.z, 32); v.w += __shfl_xor(v.w, 32); \
    } while (0)
    RED4(s); RED4(q);
    #undef RED4
    if (lane < 16) { sred[wave][lane] = s; sred[wave][16 + lane] = q; }
    __syncthreads();

    if (threadIdx.x < 16) {
        float4 ts = make_float4(0.f, 0.f, 0.f, 0.f);
        float4 tq = make_float4(0.f, 0.f, 0.f, 0.f);
        #pragma unroll
        for (int w = 0; w < 4; ++w) {
            float4 a = sred[w][threadIdx.x];
            float4 b = sred[w][16 + threadIdx.x];
            ts.x += a.x; ts.y += a.y; ts.z += a.z; ts.w += a.w;
            tq.x += b.x; tq.y += b.y; tq.z += b.z; tq.w += b.w;
        }
        const int cc = threadIdx.x * 4;
        unsafeAtomicAdd(&stats[cc + 0], ts.x);
        unsafeAtomicAdd(&stats[cc + 1], ts.y);
        unsafeAtomicAdd(&stats[cc + 2], ts.z);
        unsafeAtomicAdd(&stats[cc + 3], ts.w);
        unsafeAtomicAdd(&stats[64 + cc + 0], tq.x);
        unsafeAtomicAdd(&stats[64 + cc + 1], tq.y);
        unsafeAtomicAdd(&stats[64 + cc + 2], tq.z);
        unsafeAtomicAdd(&stats[64 + cc + 3], tq.w);
    }
}

// ---------------------------------------------------------------------------
// LEGACY PATH (fallback if workspace too small): verified kernels.
// ---------------------------------------------------------------------------
__global__ __launch_bounds__(256) void conv_kernel(
    const float* __restrict__ feats,
    const float* __restrict__ W,
    const int*   __restrict__ in_map,
    const int*   __restrict__ out_map,
    float*       __restrict__ out)
{
    const int k    = blockIdx.y;
    const int lane = threadIdx.x & 63;
    const int wave = threadIdx.x >> 6;

    __shared__ float4 fr4[4][2][16];

    float wreg[C];
    const float* Wk = W + (size_t)k * C * C;
    #pragma unroll
    for (int i = 0; i < C; ++i) wreg[i] = Wk[i * C + lane];

    const int pair_base = (blockIdx.x * 4 + wave) * 64;
    const int my_pair   = pair_base + lane;
    const int my_im = in_map[(size_t)k * MPAIR + my_pair];
    const int my_om = out_map[(size_t)k * MPAIR + my_pair];

    int im0 = __builtin_amdgcn_readlane(my_im, 0);
    float fcur = feats[(size_t)im0 * C + lane];

    for (int p = 0; p < 64; ++p) {
        const int om  = __builtin_amdgcn_readlane(my_om, p);
        const int buf = p & 1;

        ((float*)&fr4[wave][buf][0])[lane] = fcur;

        if (p < 63) {
            int imn = __builtin_amdgcn_readlane(my_im, p + 1);
            fcur = feats[(size_t)imn * C + lane];
        }

        float acc = 0.f;
        #pragma unroll
        for (int jq = 0; jq < 16; ++jq) {
            float4 f = fr4[wave][buf][jq];
            acc = fmaf(f.x, wreg[4*jq+0], acc);
            acc = fmaf(f.y, wreg[4*jq+1], acc);
            acc = fmaf(f.z, wreg[4*jq+2], acc);
            acc = fmaf(f.w, wreg[4*jq+3], acc);
        }
        unsafeAtomicAdd(&out[(size_t)om * C + lane], acc);
    }
}

__global__ __launch_bounds__(256) void stats_kernel(
    const float* __restrict__ out, float* __restrict__ stats)
{
    __shared__ float4 s_sum[256], s_sq[256];
    const int col4 = threadIdx.x & 15;
    const int rowg = threadIdx.x >> 4;

    float4 s = make_float4(0.f, 0.f, 0.f, 0.f);
    float4 q = make_float4(0.f, 0.f, 0.f, 0.f);
    for (int row = blockIdx.x * 16 + rowg; row < N_OUT; row += gridDim.x * 16) {
        float4 v = *(const float4*)(out + (size_t)row * C + col4 * 4);
        s.x += v.x; s.y += v.y; s.z += v.z; s.w += v.w;
        q.x = fmaf(v.x, v.x, q.x); q.y = fmaf(v.y, v.y, q.y);
        q.z = fmaf(v.z, v.z, q.z); q.w = fmaf(v.w, v.w, q.w);
    }
    s_sum[threadIdx.x] = s; s_sq[threadIdx.x] = q;
    __syncthreads();

    if (threadIdx.x < 16) {
        float4 ts = make_float4(0.f, 0.f, 0.f, 0.f);
        float4 tq = make_float4(0.f, 0.f, 0.f, 0.f);
        for (int jq = 0; jq < 16; ++jq) {
            float4 a = s_sum[jq * 16 + threadIdx.x];
            float4 b = s_sq [jq * 16 + threadIdx.x];
            ts.x += a.x; ts.y += a.y; ts.z += a.z; ts.w += a.w;
            tq.x += b.x; tq.y += b.y; tq.z += b.z; tq.w += b.w;
        }
        const int c0 = threadIdx.x * 4;
        unsafeAtomicAdd(&stats[c0 + 0], ts.x);
        unsafeAtomicAdd(&stats[c0 + 1], ts.y);
        unsafeAtomicAdd(&stats[c0 + 2], ts.z);
        unsafeAtomicAdd(&stats[c0 + 3], ts.w);
        unsafeAtomicAdd(&stats[64 + c0 + 0], tq.x);
        unsafeAtomicAdd(&stats[64 + c0 + 1], tq.y);
        unsafeAtomicAdd(&stats[64 + c0 + 2], tq.z);
        unsafeAtomicAdd(&stats[64 + c0 + 3], tq.w);
    }
}

// ---------------------------------------------------------------------------
// In-place BN (affine) + LeakyReLU (shared by both paths).
// ---------------------------------------------------------------------------
__global__ __launch_bounds__(256) void bn_kernel(
    float* __restrict__ out,
    const float* __restrict__ stats,
    const float* __restrict__ gamma,
    const float* __restrict__ beta)
{
    __shared__ __align__(16) float s_scale[C];
    __shared__ __align__(16) float s_shift[C];
    if (threadIdx.x < C) {
        const float inv_n = 1.0f / (float)N_OUT;
        float mean = stats[threadIdx.x] * inv_n;
        float var  = stats[C + threadIdx.x] * inv_n - mean * mean;
        float sc   = gamma[threadIdx.x] * rsqrtf(var + EPS);
        s_scale[threadIdx.x] = sc;
        s_shift[threadIdx.x] = beta[threadIdx.x] - mean * sc;
    }
    __syncthreads();

    const int col4 = threadIdx.x & 15;
    const int rowg = threadIdx.x >> 4;
    const float4 sc4 = *(const float4*)&s_scale[col4 * 4];
    const float4 sh4 = *(const float4*)&s_shift[col4 * 4];

    for (int row = blockIdx.x * 16 + rowg; row < N_OUT; row += gridDim.x * 16) {
        float4* p = (float4*)(out + (size_t)row * C + col4 * 4);
        float4 v = *p;
        v.x = fmaf(v.x, sc4.x, sh4.x);
        v.y = fmaf(v.y, sc4.y, sh4.y);
        v.z = fmaf(v.z, sc4.z, sh4.z);
        v.w = fmaf(v.w, sc4.w, sh4.w);
        v.x = v.x >= 0.f ? v.x : NEG_SLOPE * v.x;
        v.y = v.y >= 0.f ? v.y : NEG_SLOPE * v.y;
        v.z = v.z >= 0.f ? v.z : NEG_SLOPE * v.z;
        v.w = v.w >= 0.f ? v.w : NEG_SLOPE * v.w;
        *p = v;
    }
}

extern "C" void kernel_launch(void* const* d_in, const int* in_sizes, int n_in,
                              void* d_out, int out_size, void* d_ws, size_t ws_size,
                              hipStream_t stream) {
    const float* feats  = (const float*)d_in[0];
    const float* W      = (const float*)d_in[1];
    const float* gamma  = (const float*)d_in[2];
    const float* beta   = (const float*)d_in[3];
    const int*  in_map  = (const int*)d_in[4];
    const int*  out_map = (const int*)d_in[5];
    // d_in[6] = num_out (known constant N_OUT)

    float* out   = (float*)d_out;
    float* stats = (float*)d_ws;                       // 128 floats @ offset 0

    const size_t CNT_OFF = 1024;
    const size_t REC_OFF = CNT_OFF + (size_t)NKEY * 4;                  // 443392
    const size_t W16_OFF = REC_OFF + (size_t)NKEY * SLOTS * 4;          // +35.4 MB
    const size_t NEEDED  = W16_OFF + (size_t)KOFF * 16 * 64 * 8 + 1024; // ~36.1 MB

    if (ws_size >= NEEDED) {
        // --- bucketed MFMA path: matrix pipe, HW LDS atomics ---
        int* cnt = (int*)((char*)d_ws + CNT_OFF);
        unsigned int* recs = (unsigned int*)((char*)d_ws + REC_OFF);
        half4* w16 = (half4*)((char*)d_ws + W16_OFF);

        hipMemsetAsync(stats, 0, 2 * C * sizeof(float), stream);
        hipMemsetAsync(cnt, 0, (size_t)NKEY * sizeof(int), stream);
        // NOTE: no memset of out -- conv_mfma fully overwrites every row.

        w16_kernel<<<KOFF, 256, 0, stream>>>(W, w16);
        dim3 sgrid(MPAIR / 256, KOFF);
        scatter_kernel<<<sgrid, 256, 0, stream>>>(in_map, out_map, cnt, recs);
        conv_mfma_kernel<<<NBUCKET, 256, 0, stream>>>(feats, w16, cnt, recs, out, stats);
        bn_kernel<<<512, 256, 0, stream>>>(out, stats, gamma, beta);
    } else {
        // --- legacy path (verified): atomic scatter + separate stats ---
        hipMemsetAsync(out, 0, (size_t)N_OUT * C * sizeof(float), stream);
        hipMemsetAsync(stats, 0, 2 * C * sizeof(float), stream);

        dim3 cgrid(MPAIR / 256, KOFF);
        conv_kernel<<<cgrid, 256, 0, stream>>>(feats, W, in_map, out_map, out);
        stats_kernel<<<256, 256, 0, stream>>>(out, stats);
        bn_kernel<<<512, 256, 0, stream>>>(out, stats, gamma, beta);
    }
}